// Round 2
// baseline (495.415 us; speedup 1.0000x reference)
//
#include <hip/hip_runtime.h>
#include <hip/hip_bf16.h>

// Sizes (fixed for this problem)
// B=2, S=2048, D=1024, H=16, Hd=64
#define SEQ    2048
#define DMODEL 1024
#define NHEAD  16
#define HDIM   64
#define BATCH  2
#define NTOK   (BATCH * SEQ)           // 4096

// Canonical (bf16) input element counts
#define N_X   (NTOK * DMODEL)          // 4,194,304
#define N_WQ  (3 * DMODEL * DMODEL)    // 3,145,728
#define N_BQ  (3 * DMODEL)             // 3,072
#define N_WO  (DMODEL * DMODEL)        // 1,048,576
#define N_BO  (DMODEL)                 // 1,024
#define N_CANON (N_X + N_WQ + N_BQ + N_WO + N_BO)   // 8,392,704

#define NEG_SENT (-1.0e30f)

typedef __attribute__((ext_vector_type(8))) short short8;   // 8 x bf16
typedef __attribute__((ext_vector_type(4))) float f32x4;

#define MFMA_BF16(A, B, C) __builtin_amdgcn_mfma_f32_16x16x32_bf16((A), (B), (C), 0, 0, 0)

static __device__ __forceinline__ short8 load8(const __hip_bfloat16* p) {
    return *(const short8*)p;
}

// ---------------------------------------------------------------------------
// Kernel 0: dtype detector.  qkv_w is U(-1/32, 1/32): genuine bf16 elements
// have exponent field <= 122.  If the buffer is actually fp32 read as bf16,
// even-indexed elements are fp32 mantissa-low-halves: ~50% have exponent
// >= 125.  flag = 1 -> inputs are fp32.
// ---------------------------------------------------------------------------
__global__ void detect_kernel(const unsigned short* __restrict__ w, int* flag) {
    int cnt = 0;
    for (int i = threadIdx.x; i < 512; i += 64) {
        const unsigned e = (w[i] >> 7) & 0xFF;
        if (e >= 125) cnt++;
    }
#pragma unroll
    for (int o = 32; o; o >>= 1) cnt += __shfl_down(cnt, o);
    if (threadIdx.x == 0) *flag = (cnt > 8) ? 1 : 0;
}

// ---------------------------------------------------------------------------
// Kernel 0b: canonicalize all five inputs to bf16 in ws (lossless if bf16).
// dst layout: [X | Wqkv | bqkv | Wout | bout]
// ---------------------------------------------------------------------------
__global__ __launch_bounds__(256) void canon_kernel(
    const void* __restrict__ s0, const void* __restrict__ s1,
    const void* __restrict__ s2, const void* __restrict__ s3,
    const void* __restrict__ s4,
    __hip_bfloat16* __restrict__ dst, const int* __restrict__ flag)
{
    const int idx = blockIdx.x * 256 + threadIdx.x;
    if (idx >= N_CANON) return;
    const void* src;
    int off;
    if (idx < N_X)                         { src = s0; off = idx; }
    else if (idx < N_X + N_WQ)             { src = s1; off = idx - N_X; }
    else if (idx < N_X + N_WQ + N_BQ)      { src = s2; off = idx - (N_X + N_WQ); }
    else if (idx < N_X + N_WQ + N_BQ + N_WO){ src = s3; off = idx - (N_X + N_WQ + N_BQ); }
    else                                   { src = s4; off = idx - (N_X + N_WQ + N_BQ + N_WO); }
    const bool isf32 = (*flag != 0);   // uniform branch
    const float v = isf32 ? ((const float*)src)[off]
                          : __bfloat162float(((const __hip_bfloat16*)src)[off]);
    dst[idx] = __float2bfloat16(v);
}

// ---------------------------------------------------------------------------
// Kernel 1: QKV GEMM.  C[m,n] = sum_k X[m,k] * W[n,k] + bias[n]
// M=4096 (B*S), K=1024, N=3072.  Scatter epilogue:
//   n -> (c, h, d): c = n>>10, h = (n>>6)&15, d = n&63
//   c==0: Qs[b,h,s,d] = val * 0.125   (softmax scale folded into Q)
//   c==1: Kb[b,h,s,d] = val
//   c==2: Vt[b,h,d,s] = val           (V transposed for contiguous PV frags)
// ---------------------------------------------------------------------------
__global__ __launch_bounds__(256) void qkv_gemm_kernel(
    const __hip_bfloat16* __restrict__ X,     // [4096,1024]
    const __hip_bfloat16* __restrict__ W,     // [3072,1024]
    const __hip_bfloat16* __restrict__ bias,  // [3072]
    __hip_bfloat16* __restrict__ Qs,          // [B,H,S,Hd]
    __hip_bfloat16* __restrict__ Kb,          // [B,H,S,Hd]
    __hip_bfloat16* __restrict__ Vt)          // [B,H,Hd,S]
{
    constexpr int Kd = DMODEL;
    const int lane  = threadIdx.x & 63;
    const int w     = threadIdx.x >> 6;
    const int mBase = blockIdx.y * 128 + (w >> 1) * 64;
    const int nBase = blockIdx.x * 128 + (w & 1) * 64;
    const int lm    = lane & 15;          // row within 16-tile (A and B^T)
    const int lk    = (lane >> 4) * 8;    // k offset within 32-chunk

    f32x4 acc[4][4];
#pragma unroll
    for (int i = 0; i < 4; ++i)
#pragma unroll
        for (int j = 0; j < 4; ++j)
            acc[i][j] = (f32x4){0.f, 0.f, 0.f, 0.f};

    for (int k0 = 0; k0 < Kd; k0 += 32) {
        short8 a[4], b[4];
#pragma unroll
        for (int i = 0; i < 4; ++i)
            a[i] = load8(&X[(size_t)(mBase + i * 16 + lm) * Kd + k0 + lk]);
#pragma unroll
        for (int j = 0; j < 4; ++j)
            b[j] = load8(&W[(size_t)(nBase + j * 16 + lm) * Kd + k0 + lk]);
#pragma unroll
        for (int i = 0; i < 4; ++i)
#pragma unroll
            for (int j = 0; j < 4; ++j)
                acc[i][j] = MFMA_BF16(a[i], b[j], acc[i][j]);
    }

    // Epilogue: C/D layout col = lane&15, row = (lane>>4)*4 + r
    const int r0 = (lane >> 4) * 4;
#pragma unroll
    for (int j = 0; j < 4; ++j) {
        const int n  = nBase + j * 16 + lm;
        const float bv = __bfloat162float(bias[n]);
        const int c = n >> 10;
        const int h = (n >> 6) & 15;
        const int d = n & 63;
#pragma unroll
        for (int i = 0; i < 4; ++i) {
#pragma unroll
            for (int r = 0; r < 4; ++r) {
                const int m  = mBase + i * 16 + r0 + r;
                const int bb = m >> 11;          // / SEQ
                const int s  = m & (SEQ - 1);
                const int bh = bb * NHEAD + h;
                const float v = acc[i][j][r] + bv;
                if (c == 0) {
                    Qs[(size_t)(bh * SEQ + s) * HDIM + d] = __float2bfloat16(v * 0.125f);
                } else if (c == 1) {
                    Kb[(size_t)(bh * SEQ + s) * HDIM + d] = __float2bfloat16(v);
                } else {
                    Vt[(size_t)(bh * HDIM + d) * SEQ + s] = __float2bfloat16(v);
                }
            }
        }
    }
}

// ---------------------------------------------------------------------------
// Kernel 2: causal flash attention.
// Block = (qb, bh); 4 waves, wave w handles 16 q-rows at base = qb*64 + w*16.
// 32-key chunks; unified trip count across waves so __syncthreads is legal.
// No infinities anywhere (NEG_SENT sentinel) -> provably NaN-free.
// ---------------------------------------------------------------------------
__global__ __launch_bounds__(256) void attn_kernel(
    const __hip_bfloat16* __restrict__ Qs,  // [B,H,S,Hd], pre-scaled
    const __hip_bfloat16* __restrict__ Kb,  // [B,H,S,Hd]
    const __hip_bfloat16* __restrict__ Vt,  // [B,H,Hd,S]
    __hip_bfloat16* __restrict__ O)         // [B*S, D]  (cols = h*64+d)
{
    __shared__ __align__(16) __hip_bfloat16 Pbuf[4][16 * 32];

    const int lane = threadIdx.x & 63;
    const int w    = threadIdx.x >> 6;
    const int qb   = gridDim.x - 1 - blockIdx.x;   // heavy blocks first
    const int bh   = blockIdx.y;
    const int base = qb * 64 + w * 16;
    const int lm   = lane & 15;
    const int q4   = lane >> 4;
    const int lk   = q4 * 8;

    const __hip_bfloat16* Qbh = Qs + (size_t)bh * SEQ * HDIM;
    const __hip_bfloat16* Kbh = Kb + (size_t)bh * SEQ * HDIM;
    const __hip_bfloat16* Vbh = Vt + (size_t)bh * HDIM * SEQ;

    // Q fragments for this wave's 16 rows (d = 0..31 and 32..63)
    const short8 qa0 = load8(&Qbh[(size_t)(base + lm) * HDIM + lk]);
    const short8 qa1 = load8(&Qbh[(size_t)(base + lm) * HDIM + 32 + lk]);

    float m_run[4], l_run[4];
    f32x4 Oacc[4];
#pragma unroll
    for (int r = 0; r < 4; ++r) { m_run[r] = NEG_SENT; l_run[r] = 0.f; }
#pragma unroll
    for (int t = 0; t < 4; ++t) Oacc[t] = (f32x4){0.f, 0.f, 0.f, 0.f};

    const int nChunks = 2 * qb + 2;   // covers keys up to qb*64+63 for all waves
    for (int c = 0; c < nChunks; ++c) {
        const int k0 = c * 32;

        // --- scores: 16 rows x 32 keys = two C-tiles ---
        f32x4 sc[2];
        sc[0] = (f32x4){0.f, 0.f, 0.f, 0.f};
        sc[1] = (f32x4){0.f, 0.f, 0.f, 0.f};
#pragma unroll
        for (int t = 0; t < 2; ++t) {
            const short8 kb0 = load8(&Kbh[(size_t)(k0 + t * 16 + lm) * HDIM + lk]);
            const short8 kb1 = load8(&Kbh[(size_t)(k0 + t * 16 + lm) * HDIM + 32 + lk]);
            sc[t] = MFMA_BF16(qa0, kb0, sc[t]);
            sc[t] = MFMA_BF16(qa1, kb1, sc[t]);
        }

        // --- causal mask (diagonal or fully-masked chunk) ---
        if (k0 + 31 > base) {
#pragma unroll
            for (int t = 0; t < 2; ++t) {
                const int col = k0 + t * 16 + lm;
#pragma unroll
                for (int r = 0; r < 4; ++r) {
                    const int row = base + q4 * 4 + r;
                    if (col > row) sc[t][r] = NEG_SENT;
                }
            }
        }

        // --- online softmax (fp32) ---
        float mn[4], rs[4];
#pragma unroll
        for (int r = 0; r < 4; ++r) {
            float mx = fmaxf(sc[0][r], sc[1][r]);
            mx = fmaxf(mx, __shfl_xor(mx, 1));
            mx = fmaxf(mx, __shfl_xor(mx, 2));
            mx = fmaxf(mx, __shfl_xor(mx, 4));
            mx = fmaxf(mx, __shfl_xor(mx, 8));
            mn[r] = fmaxf(m_run[r], mx);
            const float p0 = __expf(sc[0][r] - mn[r]);
            const float p1 = __expf(sc[1][r] - mn[r]);
            sc[0][r] = p0;
            sc[1][r] = p1;
            float s = p0 + p1;
            s += __shfl_xor(s, 1);
            s += __shfl_xor(s, 2);
            s += __shfl_xor(s, 4);
            s += __shfl_xor(s, 8);
            rs[r] = s;
        }
#pragma unroll
        for (int r = 0; r < 4; ++r) {
            const float alpha = __expf(m_run[r] - mn[r]);
            l_run[r] = l_run[r] * alpha + rs[r];
            m_run[r] = mn[r];
#pragma unroll
            for (int t = 0; t < 4; ++t) Oacc[t][r] *= alpha;
        }

        // --- P (C-layout, fp32) -> LDS (bf16) -> A-fragment ---
        __hip_bfloat16* P = Pbuf[w];
#pragma unroll
        for (int t = 0; t < 2; ++t)
#pragma unroll
            for (int r = 0; r < 4; ++r)
                P[(q4 * 4 + r) * 32 + t * 16 + lm] = __float2bfloat16(sc[t][r]);
        __syncthreads();
        const short8 pa = *(const short8*)&P[lm * 32 + lk];

        // --- PV: out 16x64, contraction over 32 keys ---
#pragma unroll
        for (int t = 0; t < 4; ++t) {
            const short8 vb = load8(&Vbh[(size_t)(t * 16 + lm) * SEQ + k0 + lk]);
            Oacc[t] = MFMA_BF16(pa, vb, Oacc[t]);
        }
        __syncthreads();   // protect P buffer before next iteration's write
    }

    // --- epilogue: O /= l, store [b*S+s, h*64+d] as bf16 ---
    const int b = bh >> 4;
    const int h = bh & 15;
#pragma unroll
    for (int r = 0; r < 4; ++r) {
        const float inv = 1.0f / l_run[r];
        const size_t m = (size_t)b * SEQ + base + q4 * 4 + r;
#pragma unroll
        for (int t = 0; t < 4; ++t)
            O[m * DMODEL + h * 64 + t * 16 + lm] = __float2bfloat16(Oacc[t][r] * inv);
    }
}

// ---------------------------------------------------------------------------
// Kernel 3: out projection.  out[m,n] = sum_k A[m,k] * W[n,k] + bias[n]
// M=4096, K=1024, N=1024.  Output dtype selected by flag (fp32 or bf16).
// ---------------------------------------------------------------------------
__global__ __launch_bounds__(256) void proj_gemm_kernel(
    const __hip_bfloat16* __restrict__ A,     // [4096,1024]
    const __hip_bfloat16* __restrict__ W,     // [1024,1024]
    const __hip_bfloat16* __restrict__ bias,  // [1024]
    void* __restrict__ outv,                  // [4096,1024] fp32 or bf16
    const int* __restrict__ flag)
{
    constexpr int Kd = DMODEL;
    const int lane  = threadIdx.x & 63;
    const int w     = threadIdx.x >> 6;
    const int mBase = blockIdx.y * 128 + (w >> 1) * 64;
    const int nBase = blockIdx.x * 128 + (w & 1) * 64;
    const int lm    = lane & 15;
    const int lk    = (lane >> 4) * 8;
    const bool f32out = (*flag != 0);   // uniform

    f32x4 acc[4][4];
#pragma unroll
    for (int i = 0; i < 4; ++i)
#pragma unroll
        for (int j = 0; j < 4; ++j)
            acc[i][j] = (f32x4){0.f, 0.f, 0.f, 0.f};

    for (int k0 = 0; k0 < Kd; k0 += 32) {
        short8 a[4], b[4];
#pragma unroll
        for (int i = 0; i < 4; ++i)
            a[i] = load8(&A[(size_t)(mBase + i * 16 + lm) * Kd + k0 + lk]);
#pragma unroll
        for (int j = 0; j < 4; ++j)
            b[j] = load8(&W[(size_t)(nBase + j * 16 + lm) * Kd + k0 + lk]);
#pragma unroll
        for (int i = 0; i < 4; ++i)
#pragma unroll
            for (int j = 0; j < 4; ++j)
                acc[i][j] = MFMA_BF16(a[i], b[j], acc[i][j]);
    }

    const int r0 = (lane >> 4) * 4;
#pragma unroll
    for (int j = 0; j < 4; ++j) {
        const int n = nBase + j * 16 + lm;
        const float bv = __bfloat162float(bias[n]);
#pragma unroll
        for (int i = 0; i < 4; ++i) {
#pragma unroll
            for (int r = 0; r < 4; ++r) {
                const size_t m = mBase + i * 16 + r0 + r;
                const float v = acc[i][j][r] + bv;
                if (f32out) ((float*)outv)[m * DMODEL + n] = v;
                else ((__hip_bfloat16*)outv)[m * DMODEL + n] = __float2bfloat16(v);
            }
        }
    }
}

// ---------------------------------------------------------------------------
extern "C" void kernel_launch(void* const* d_in, const int* in_sizes, int n_in,
                              void* d_out, int out_size, void* d_ws, size_t ws_size,
                              hipStream_t stream) {
    // Workspace layout (all 16B-aligned):
    //   [flag:256B][canonical bf16 inputs: X|Wq|bq|Wo|bo][Qs][Kb][Vt][Ao]
    char* wsb = (char*)d_ws;
    int* flag = (int*)wsb;
    __hip_bfloat16* canon = (__hip_bfloat16*)(wsb + 256);
    __hip_bfloat16* Xc = canon;
    __hip_bfloat16* Wq = Xc + N_X;
    __hip_bfloat16* Bq = Wq + N_WQ;
    __hip_bfloat16* Wo = Bq + N_BQ;
    __hip_bfloat16* Bo = Wo + N_WO;

    const size_t nBH = (size_t)BATCH * NHEAD * SEQ * HDIM;  // 4 Mi elements
    __hip_bfloat16* Qs = Bo + N_BO;
    __hip_bfloat16* Kb = Qs + nBH;
    __hip_bfloat16* Vt = Kb + nBH;
    __hip_bfloat16* Ao = Vt + nBH;   // attention output, [B*S, D]

    // 0) detect input dtype (fp32 vs bf16) from qkv_w's value distribution
    detect_kernel<<<1, 64, 0, stream>>>((const unsigned short*)d_in[1], flag);
    // 0b) canonicalize all inputs to bf16
    canon_kernel<<<(N_CANON + 255) / 256, 256, 0, stream>>>(
        d_in[0], d_in[1], d_in[2], d_in[3], d_in[4], canon, flag);

    // 1) QKV GEMM: M=4096, N=3072
    {
        dim3 grid(3 * DMODEL / 128, NTOK / 128);
        qkv_gemm_kernel<<<grid, 256, 0, stream>>>(Xc, Wq, Bq, Qs, Kb, Vt);
    }
    // 2) Attention: grid (S/64, B*H)
    {
        dim3 grid(SEQ / 64, BATCH * NHEAD);
        attn_kernel<<<grid, 256, 0, stream>>>(Qs, Kb, Vt, Ao);
    }
    // 3) Out projection: M=4096, N=1024, dtype per flag
    {
        dim3 grid(DMODEL / 128, NTOK / 128);
        proj_gemm_kernel<<<grid, 256, 0, stream>>>(Ao, Wo, Bo, d_out, flag);
    }
}

// Round 3
// 418.270 us; speedup vs baseline: 1.1844x; 1.1844x over previous
//
#include <hip/hip_runtime.h>
#include <hip/hip_bf16.h>

// Sizes (fixed for this problem)
// B=2, S=2048, D=1024, H=16, Hd=64
#define SEQ    2048
#define DMODEL 1024
#define NHEAD  16
#define HDIM   64
#define BATCH  2
#define NTOK   (BATCH * SEQ)           // 4096

// Canonical (bf16) input element counts
#define N_X   (NTOK * DMODEL)          // 4,194,304
#define N_WQ  (3 * DMODEL * DMODEL)    // 3,145,728
#define N_BQ  (3 * DMODEL)             // 3,072
#define N_WO  (DMODEL * DMODEL)        // 1,048,576
#define N_BO  (DMODEL)                 // 1,024
#define N_CANON (N_X + N_WQ + N_BQ + N_WO + N_BO)   // 8,392,704

#define NEG_SENT (-1.0e30f)
// softmax scale folded into Q, in exp2 domain: (1/8) * log2(e)
#define QSCALE 0.1803368801111f

typedef __attribute__((ext_vector_type(8))) short short8;   // 8 x bf16
typedef __attribute__((ext_vector_type(4))) float f32x4;

#define MFMA_BF16(A, B, C) __builtin_amdgcn_mfma_f32_16x16x32_bf16((A), (B), (C), 0, 0, 0)

static __device__ __forceinline__ short8 load8(const __hip_bfloat16* p) {
    return *(const short8*)p;
}

// ---------------------------------------------------------------------------
// Kernel 0: dtype detector.  qkv_w is U(-1/32, 1/32): genuine bf16 elements
// have exponent field <= 122.  If the buffer is actually fp32 read as bf16,
// even-indexed elements are fp32 mantissa-low-halves: ~50% have exponent
// >= 125.  flag = 1 -> inputs are fp32.  (Round 2 confirmed: fp32.)
// ---------------------------------------------------------------------------
__global__ void detect_kernel(const unsigned short* __restrict__ w, int* flag) {
    int cnt = 0;
    for (int i = threadIdx.x; i < 512; i += 64) {
        const unsigned e = (w[i] >> 7) & 0xFF;
        if (e >= 125) cnt++;
    }
#pragma unroll
    for (int o = 32; o; o >>= 1) cnt += __shfl_down(cnt, o);
    if (threadIdx.x == 0) *flag = (cnt > 8) ? 1 : 0;
}

// ---------------------------------------------------------------------------
// Kernel 0b: canonicalize all five inputs to bf16 in ws (lossless if bf16).
// dst layout: [X | Wqkv | bqkv | Wout | bout]
// ---------------------------------------------------------------------------
__global__ __launch_bounds__(256) void canon_kernel(
    const void* __restrict__ s0, const void* __restrict__ s1,
    const void* __restrict__ s2, const void* __restrict__ s3,
    const void* __restrict__ s4,
    __hip_bfloat16* __restrict__ dst, const int* __restrict__ flag)
{
    const int idx = blockIdx.x * 256 + threadIdx.x;
    if (idx >= N_CANON) return;
    const void* src;
    int off;
    if (idx < N_X)                         { src = s0; off = idx; }
    else if (idx < N_X + N_WQ)             { src = s1; off = idx - N_X; }
    else if (idx < N_X + N_WQ + N_BQ)      { src = s2; off = idx - (N_X + N_WQ); }
    else if (idx < N_X + N_WQ + N_BQ + N_WO){ src = s3; off = idx - (N_X + N_WQ + N_BQ); }
    else                                   { src = s4; off = idx - (N_X + N_WQ + N_BQ + N_WO); }
    const bool isf32 = (*flag != 0);   // uniform branch
    const float v = isf32 ? ((const float*)src)[off]
                          : __bfloat162float(((const __hip_bfloat16*)src)[off]);
    dst[idx] = __float2bfloat16(v);
}

// ---------------------------------------------------------------------------
// Kernel 1: QKV GEMM.  C[m,n] = sum_k X[m,k] * W[n,k] + bias[n]
// M=4096 (B*S), K=1024, N=3072.  Scatter epilogue:
//   c==0: Qs[b,h,s,d] = val * QSCALE   (softmax+log2e scale folded into Q)
//   c==1: Kb[b,h,s,d] = val
//   c==2: Vt[b,h,d,s] = val            (V transposed for contiguous PV frags)
// ---------------------------------------------------------------------------
__global__ __launch_bounds__(256) void qkv_gemm_kernel(
    const __hip_bfloat16* __restrict__ X,     // [4096,1024]
    const __hip_bfloat16* __restrict__ W,     // [3072,1024]
    const __hip_bfloat16* __restrict__ bias,  // [3072]
    __hip_bfloat16* __restrict__ Qs,          // [B,H,S,Hd]
    __hip_bfloat16* __restrict__ Kb,          // [B,H,S,Hd]
    __hip_bfloat16* __restrict__ Vt)          // [B,H,Hd,S]
{
    constexpr int Kd = DMODEL;
    const int lane  = threadIdx.x & 63;
    const int w     = threadIdx.x >> 6;
    const int mBase = blockIdx.y * 128 + (w >> 1) * 64;
    const int nBase = blockIdx.x * 128 + (w & 1) * 64;
    const int lm    = lane & 15;          // row within 16-tile (A and B^T)
    const int lk    = (lane >> 4) * 8;    // k offset within 32-chunk

    f32x4 acc[4][4];
#pragma unroll
    for (int i = 0; i < 4; ++i)
#pragma unroll
        for (int j = 0; j < 4; ++j)
            acc[i][j] = (f32x4){0.f, 0.f, 0.f, 0.f};

    for (int k0 = 0; k0 < Kd; k0 += 32) {
        short8 a[4], b[4];
#pragma unroll
        for (int i = 0; i < 4; ++i)
            a[i] = load8(&X[(size_t)(mBase + i * 16 + lm) * Kd + k0 + lk]);
#pragma unroll
        for (int j = 0; j < 4; ++j)
            b[j] = load8(&W[(size_t)(nBase + j * 16 + lm) * Kd + k0 + lk]);
#pragma unroll
        for (int i = 0; i < 4; ++i)
#pragma unroll
            for (int j = 0; j < 4; ++j)
                acc[i][j] = MFMA_BF16(a[i], b[j], acc[i][j]);
    }

    // Epilogue: C/D layout col = lane&15, row = (lane>>4)*4 + r
    const int r0 = (lane >> 4) * 4;
#pragma unroll
    for (int j = 0; j < 4; ++j) {
        const int n  = nBase + j * 16 + lm;
        const float bv = __bfloat162float(bias[n]);
        const int c = n >> 10;
        const int h = (n >> 6) & 15;
        const int d = n & 63;
#pragma unroll
        for (int i = 0; i < 4; ++i) {
#pragma unroll
            for (int r = 0; r < 4; ++r) {
                const int m  = mBase + i * 16 + r0 + r;
                const int bb = m >> 11;          // / SEQ
                const int s  = m & (SEQ - 1);
                const int bh = bb * NHEAD + h;
                const float v = acc[i][j][r] + bv;
                if (c == 0) {
                    Qs[(size_t)(bh * SEQ + s) * HDIM + d] = __float2bfloat16(v * QSCALE);
                } else if (c == 1) {
                    Kb[(size_t)(bh * SEQ + s) * HDIM + d] = __float2bfloat16(v);
                } else {
                    Vt[(size_t)(bh * HDIM + d) * SEQ + s] = __float2bfloat16(v);
                }
            }
        }
    }
}

// ---------------------------------------------------------------------------
// Kernel 2: causal flash attention, single-wave blocks.
// Block = 1 wave = 32 q rows (2 A-tiles).  K-chunk = 64 keys (4 K-tiles).
// No __syncthreads: per-block LDS is wave-private; the LDS pipe is in-order
// per wave and the compiler preserves program order on may-alias DS ops.
// P round-trip uses an XOR-swizzled layout: pitch 72 elems, col ^= q4*16
// (q4 = (row>>2)&3) -> conflict-free b16 writes, 16B-aligned b128 reads.
// Softmax in exp2 domain (log2e folded into Q scale).
// ---------------------------------------------------------------------------
#define P_PITCH 72
__global__ __launch_bounds__(64) void attn_kernel(
    const __hip_bfloat16* __restrict__ Qs,  // [B,H,S,Hd], pre-scaled
    const __hip_bfloat16* __restrict__ Kb,  // [B,H,S,Hd]
    const __hip_bfloat16* __restrict__ Vt,  // [B,H,Hd,S]
    __hip_bfloat16* __restrict__ O)         // [B*S, D]  (cols = h*64+d)
{
    __shared__ __align__(16) __hip_bfloat16 P[32 * P_PITCH];

    const int lane = threadIdx.x;
    const int qb   = gridDim.x - 1 - blockIdx.x;   // heavy blocks first
    const int bh   = blockIdx.y;
    const int base = qb * 32;
    const int lm   = lane & 15;
    const int q4   = lane >> 4;
    const int lk   = q4 * 8;

    const __hip_bfloat16* Qbh = Qs + (size_t)bh * SEQ * HDIM;
    const __hip_bfloat16* Kbh = Kb + (size_t)bh * SEQ * HDIM;
    const __hip_bfloat16* Vbh = Vt + (size_t)bh * HDIM * SEQ;

    // Q fragments: 2 q-tiles x 2 k-halves
    short8 qa[2][2];
#pragma unroll
    for (int i = 0; i < 2; ++i)
#pragma unroll
        for (int h = 0; h < 2; ++h)
            qa[i][h] = load8(&Qbh[(size_t)(base + i * 16 + lm) * HDIM + h * 32 + lk]);

    float m_run[2][4], l_run[2][4];
    f32x4 Oacc[2][4];    // [q-tile][d-tile]
#pragma unroll
    for (int i = 0; i < 2; ++i)
#pragma unroll
        for (int r = 0; r < 4; ++r) { m_run[i][r] = NEG_SENT; l_run[i][r] = 0.f; }
#pragma unroll
    for (int i = 0; i < 2; ++i)
#pragma unroll
        for (int t = 0; t < 4; ++t) Oacc[i][t] = (f32x4){0.f, 0.f, 0.f, 0.f};

    const int nChunks = (base + 32 + 63) >> 6;
    for (int c = 0; c < nChunks; ++c) {
        const int k0 = c * 64;

        // --- scores: 32 rows x 64 keys = 8 C-tiles, 16 MFMAs ---
        f32x4 sc[2][4];
#pragma unroll
        for (int i = 0; i < 2; ++i)
#pragma unroll
            for (int t = 0; t < 4; ++t) sc[i][t] = (f32x4){0.f, 0.f, 0.f, 0.f};
#pragma unroll
        for (int t = 0; t < 4; ++t) {
            const short8 kb0 = load8(&Kbh[(size_t)(k0 + t * 16 + lm) * HDIM + lk]);
            const short8 kb1 = load8(&Kbh[(size_t)(k0 + t * 16 + lm) * HDIM + 32 + lk]);
#pragma unroll
            for (int i = 0; i < 2; ++i) {
                sc[i][t] = MFMA_BF16(qa[i][0], kb0, sc[i][t]);
                sc[i][t] = MFMA_BF16(qa[i][1], kb1, sc[i][t]);
            }
        }

        // --- causal mask (only last chunk can touch the diagonal) ---
        if (k0 + 63 > base) {
#pragma unroll
            for (int i = 0; i < 2; ++i)
#pragma unroll
                for (int t = 0; t < 4; ++t) {
                    const int col = k0 + t * 16 + lm;
#pragma unroll
                    for (int r = 0; r < 4; ++r) {
                        const int row = base + i * 16 + q4 * 4 + r;
                        if (col > row) sc[i][t][r] = NEG_SENT;
                    }
                }
        }

        // --- online softmax (fp32, exp2 domain) ---
#pragma unroll
        for (int i = 0; i < 2; ++i) {
#pragma unroll
            for (int r = 0; r < 4; ++r) {
                float mx = fmaxf(fmaxf(sc[i][0][r], sc[i][1][r]),
                                 fmaxf(sc[i][2][r], sc[i][3][r]));
                mx = fmaxf(mx, __shfl_xor(mx, 1));
                mx = fmaxf(mx, __shfl_xor(mx, 2));
                mx = fmaxf(mx, __shfl_xor(mx, 4));
                mx = fmaxf(mx, __shfl_xor(mx, 8));
                const float mn = fmaxf(m_run[i][r], mx);
                const float alpha = exp2f(m_run[i][r] - mn);
                float s = 0.f;
#pragma unroll
                for (int t = 0; t < 4; ++t) {
                    const float p = exp2f(sc[i][t][r] - mn);
                    sc[i][t][r] = p;
                    s += p;
                }
                s += __shfl_xor(s, 1);
                s += __shfl_xor(s, 2);
                s += __shfl_xor(s, 4);
                s += __shfl_xor(s, 8);
                l_run[i][r] = l_run[i][r] * alpha + s;
                m_run[i][r] = mn;
#pragma unroll
                for (int t = 0; t < 4; ++t) Oacc[i][t][r] *= alpha;
            }
        }

        // --- P (C-layout) -> LDS (bf16, swizzled) ---
#pragma unroll
        for (int i = 0; i < 2; ++i)
#pragma unroll
            for (int t = 0; t < 4; ++t)
#pragma unroll
                for (int r = 0; r < 4; ++r) {
                    const int row = i * 16 + q4 * 4 + r;
                    const int col = (t * 16 + lm) ^ (q4 * 16);  // q4 == (row>>2)&3
                    P[row * P_PITCH + col] = __float2bfloat16(sc[i][t][r]);
                }

        // --- PV: A-frags from LDS, B-frags from Vt, 16 MFMAs ---
#pragma unroll
        for (int h = 0; h < 2; ++h) {
            short8 pa[2];
#pragma unroll
            for (int i = 0; i < 2; ++i) {
                const int col = (h * 32 + lk) ^ (((lm >> 2) & 3) * 16);
                pa[i] = *(const short8*)&P[(i * 16 + lm) * P_PITCH + col];
            }
#pragma unroll
            for (int t = 0; t < 4; ++t) {
                const short8 vb = load8(&Vbh[(size_t)(t * 16 + lm) * SEQ + k0 + h * 32 + lk]);
#pragma unroll
                for (int i = 0; i < 2; ++i)
                    Oacc[i][t] = MFMA_BF16(pa[i], vb, Oacc[i][t]);
            }
        }
    }

    // --- epilogue: O /= l, store [b*S+s, h*64+d] as bf16 ---
    const int b = bh >> 4;
    const int h = bh & 15;
#pragma unroll
    for (int i = 0; i < 2; ++i)
#pragma unroll
        for (int r = 0; r < 4; ++r) {
            const float inv = 1.0f / l_run[i][r];
            const size_t m = (size_t)b * SEQ + base + i * 16 + q4 * 4 + r;
#pragma unroll
            for (int t = 0; t < 4; ++t)
                O[m * DMODEL + h * 64 + t * 16 + lm] = __float2bfloat16(Oacc[i][t][r] * inv);
        }
}

// ---------------------------------------------------------------------------
// Kernel 3: out projection.  out[m,n] = sum_k A[m,k] * W[n,k] + bias[n]
// M=4096, K=1024, N=1024.  Output dtype selected by flag (fp32 or bf16).
// ---------------------------------------------------------------------------
__global__ __launch_bounds__(256) void proj_gemm_kernel(
    const __hip_bfloat16* __restrict__ A,     // [4096,1024]
    const __hip_bfloat16* __restrict__ W,     // [1024,1024]
    const __hip_bfloat16* __restrict__ bias,  // [1024]
    void* __restrict__ outv,                  // [4096,1024] fp32 or bf16
    const int* __restrict__ flag)
{
    constexpr int Kd = DMODEL;
    const int lane  = threadIdx.x & 63;
    const int w     = threadIdx.x >> 6;
    const int mBase = blockIdx.y * 128 + (w >> 1) * 64;
    const int nBase = blockIdx.x * 128 + (w & 1) * 64;
    const int lm    = lane & 15;
    const int lk    = (lane >> 4) * 8;
    const bool f32out = (*flag != 0);   // uniform

    f32x4 acc[4][4];
#pragma unroll
    for (int i = 0; i < 4; ++i)
#pragma unroll
        for (int j = 0; j < 4; ++j)
            acc[i][j] = (f32x4){0.f, 0.f, 0.f, 0.f};

    for (int k0 = 0; k0 < Kd; k0 += 32) {
        short8 a[4], b[4];
#pragma unroll
        for (int i = 0; i < 4; ++i)
            a[i] = load8(&A[(size_t)(mBase + i * 16 + lm) * Kd + k0 + lk]);
#pragma unroll
        for (int j = 0; j < 4; ++j)
            b[j] = load8(&W[(size_t)(nBase + j * 16 + lm) * Kd + k0 + lk]);
#pragma unroll
        for (int i = 0; i < 4; ++i)
#pragma unroll
            for (int j = 0; j < 4; ++j)
                acc[i][j] = MFMA_BF16(a[i], b[j], acc[i][j]);
    }

    const int r0 = (lane >> 4) * 4;
#pragma unroll
    for (int j = 0; j < 4; ++j) {
        const int n = nBase + j * 16 + lm;
        const float bv = __bfloat162float(bias[n]);
#pragma unroll
        for (int i = 0; i < 4; ++i) {
#pragma unroll
            for (int r = 0; r < 4; ++r) {
                const size_t m = mBase + i * 16 + r0 + r;
                const float v = acc[i][j][r] + bv;
                if (f32out) ((float*)outv)[m * DMODEL + n] = v;
                else ((__hip_bfloat16*)outv)[m * DMODEL + n] = __float2bfloat16(v);
            }
        }
    }
}

// ---------------------------------------------------------------------------
extern "C" void kernel_launch(void* const* d_in, const int* in_sizes, int n_in,
                              void* d_out, int out_size, void* d_ws, size_t ws_size,
                              hipStream_t stream) {
    // Workspace layout (all 16B-aligned):
    //   [flag:256B][canonical bf16 inputs: X|Wq|bq|Wo|bo][Qs][Kb][Vt][Ao]
    char* wsb = (char*)d_ws;
    int* flag = (int*)wsb;
    __hip_bfloat16* canon = (__hip_bfloat16*)(wsb + 256);
    __hip_bfloat16* Xc = canon;
    __hip_bfloat16* Wq = Xc + N_X;
    __hip_bfloat16* Bq = Wq + N_WQ;
    __hip_bfloat16* Wo = Bq + N_BQ;
    __hip_bfloat16* Bo = Wo + N_WO;

    const size_t nBH = (size_t)BATCH * NHEAD * SEQ * HDIM;  // 4 Mi elements
    __hip_bfloat16* Qs = Bo + N_BO;
    __hip_bfloat16* Kb = Qs + nBH;
    __hip_bfloat16* Vt = Kb + nBH;
    __hip_bfloat16* Ao = Vt + nBH;   // attention output, [B*S, D]

    // 0) detect input dtype (fp32 vs bf16) from qkv_w's value distribution
    detect_kernel<<<1, 64, 0, stream>>>((const unsigned short*)d_in[1], flag);
    // 0b) canonicalize all inputs to bf16
    canon_kernel<<<(N_CANON + 255) / 256, 256, 0, stream>>>(
        d_in[0], d_in[1], d_in[2], d_in[3], d_in[4], canon, flag);

    // 1) QKV GEMM: M=4096, N=3072
    {
        dim3 grid(3 * DMODEL / 128, NTOK / 128);
        qkv_gemm_kernel<<<grid, 256, 0, stream>>>(Xc, Wq, Bq, Qs, Kb, Vt);
    }
    // 2) Attention: grid (S/32, B*H), single-wave blocks
    {
        dim3 grid(SEQ / 32, BATCH * NHEAD);
        attn_kernel<<<grid, 64, 0, stream>>>(Qs, Kb, Vt, Ao);
    }
    // 3) Out projection: M=4096, N=1024, dtype per flag
    {
        dim3 grid(DMODEL / 128, NTOK / 128);
        proj_gemm_kernel<<<grid, 256, 0, stream>>>(Ao, Wo, Bo, d_out, flag);
    }
}

// Round 4
// 382.021 us; speedup vs baseline: 1.2968x; 1.0949x over previous
//
#include <hip/hip_runtime.h>
#include <hip/hip_bf16.h>

// Sizes (fixed for this problem)
// B=2, S=2048, D=1024, H=16, Hd=64
#define SEQ    2048
#define DMODEL 1024
#define NHEAD  16
#define HDIM   64
#define BATCH  2
#define NTOK   (BATCH * SEQ)           // 4096

// Canonical (bf16) input element counts
#define N_X   (NTOK * DMODEL)          // 4,194,304
#define N_WQ  (3 * DMODEL * DMODEL)    // 3,145,728
#define N_BQ  (3 * DMODEL)             // 3,072
#define N_WO  (DMODEL * DMODEL)        // 1,048,576
#define N_BO  (DMODEL)                 // 1,024
#define N_CANON (N_X + N_WQ + N_BQ + N_WO + N_BO)   // 8,392,704

#define NEG_SENT (-1.0e30f)
// softmax scale folded into Q, in exp2 domain: (1/8) * log2(e)
#define QSCALE 0.1803368801111f

typedef __attribute__((ext_vector_type(8))) short short8;   // 8 x bf16
typedef __attribute__((ext_vector_type(4))) short short4v;  // 4 x bf16 (8 B)
typedef __attribute__((ext_vector_type(4))) float f32x4;

#define MFMA_BF16(A, B, C) __builtin_amdgcn_mfma_f32_16x16x32_bf16((A), (B), (C), 0, 0, 0)

static __device__ __forceinline__ short8 load8(const __hip_bfloat16* p) {
    return *(const short8*)p;
}

// ---------------------------------------------------------------------------
// Kernel 0: dtype detector (round 2 confirmed inputs are fp32, but keep the
// runtime check so the kernel is robust either way).
// ---------------------------------------------------------------------------
__global__ void detect_kernel(const unsigned short* __restrict__ w, int* flag) {
    int cnt = 0;
    for (int i = threadIdx.x; i < 512; i += 64) {
        const unsigned e = (w[i] >> 7) & 0xFF;
        if (e >= 125) cnt++;
    }
#pragma unroll
    for (int o = 32; o; o >>= 1) cnt += __shfl_down(cnt, o);
    if (threadIdx.x == 0) *flag = (cnt > 8) ? 1 : 0;
}

// ---------------------------------------------------------------------------
// Kernel 0b: canonicalize all five inputs to bf16 in ws.
// dst layout: [X | Wqkv | bqkv | Wout | bout]
// ---------------------------------------------------------------------------
__global__ __launch_bounds__(256) void canon_kernel(
    const void* __restrict__ s0, const void* __restrict__ s1,
    const void* __restrict__ s2, const void* __restrict__ s3,
    const void* __restrict__ s4,
    __hip_bfloat16* __restrict__ dst, const int* __restrict__ flag)
{
    const int idx = blockIdx.x * 256 + threadIdx.x;
    if (idx >= N_CANON) return;
    const void* src;
    int off;
    if (idx < N_X)                         { src = s0; off = idx; }
    else if (idx < N_X + N_WQ)             { src = s1; off = idx - N_X; }
    else if (idx < N_X + N_WQ + N_BQ)      { src = s2; off = idx - (N_X + N_WQ); }
    else if (idx < N_X + N_WQ + N_BQ + N_WO){ src = s3; off = idx - (N_X + N_WQ + N_BQ); }
    else                                   { src = s4; off = idx - (N_X + N_WQ + N_BQ + N_WO); }
    const bool isf32 = (*flag != 0);   // uniform branch
    const float v = isf32 ? ((const float*)src)[off]
                          : __bfloat162float(((const __hip_bfloat16*)src)[off]);
    dst[idx] = __float2bfloat16(v);
}

// ---------------------------------------------------------------------------
// Kernel 1: QKV GEMM.  C[m,n] = sum_k X[m,k] * W[n,k] + bias[n]
// M=4096 (B*S), K=1024, N=3072.  Scatter epilogue:
//   c==0: Qs[b,h,s,d] = val * QSCALE   (softmax+log2e scale folded into Q)
//   c==1: Kb[b,h,s,d] = val
//   c==2: Vt[b,h,d,s] = val            (V transposed for contiguous PV frags)
// ---------------------------------------------------------------------------
__global__ __launch_bounds__(256) void qkv_gemm_kernel(
    const __hip_bfloat16* __restrict__ X,     // [4096,1024]
    const __hip_bfloat16* __restrict__ W,     // [3072,1024]
    const __hip_bfloat16* __restrict__ bias,  // [3072]
    __hip_bfloat16* __restrict__ Qs,          // [B,H,S,Hd]
    __hip_bfloat16* __restrict__ Kb,          // [B,H,S,Hd]
    __hip_bfloat16* __restrict__ Vt)          // [B,H,Hd,S]
{
    constexpr int Kd = DMODEL;
    const int lane  = threadIdx.x & 63;
    const int w     = threadIdx.x >> 6;
    const int mBase = blockIdx.y * 128 + (w >> 1) * 64;
    const int nBase = blockIdx.x * 128 + (w & 1) * 64;
    const int lm    = lane & 15;
    const int lk    = (lane >> 4) * 8;

    f32x4 acc[4][4];
#pragma unroll
    for (int i = 0; i < 4; ++i)
#pragma unroll
        for (int j = 0; j < 4; ++j)
            acc[i][j] = (f32x4){0.f, 0.f, 0.f, 0.f};

    for (int k0 = 0; k0 < Kd; k0 += 32) {
        short8 a[4], b[4];
#pragma unroll
        for (int i = 0; i < 4; ++i)
            a[i] = load8(&X[(size_t)(mBase + i * 16 + lm) * Kd + k0 + lk]);
#pragma unroll
        for (int j = 0; j < 4; ++j)
            b[j] = load8(&W[(size_t)(nBase + j * 16 + lm) * Kd + k0 + lk]);
#pragma unroll
        for (int i = 0; i < 4; ++i)
#pragma unroll
            for (int j = 0; j < 4; ++j)
                acc[i][j] = MFMA_BF16(a[i], b[j], acc[i][j]);
    }

    const int r0 = (lane >> 4) * 4;
#pragma unroll
    for (int j = 0; j < 4; ++j) {
        const int n  = nBase + j * 16 + lm;
        const float bv = __bfloat162float(bias[n]);
        const int c = n >> 10;
        const int h = (n >> 6) & 15;
        const int d = n & 63;
#pragma unroll
        for (int i = 0; i < 4; ++i) {
#pragma unroll
            for (int r = 0; r < 4; ++r) {
                const int m  = mBase + i * 16 + r0 + r;
                const int bb = m >> 11;          // / SEQ
                const int s  = m & (SEQ - 1);
                const int bh = bb * NHEAD + h;
                const float v = acc[i][j][r] + bv;
                if (c == 0) {
                    Qs[(size_t)(bh * SEQ + s) * HDIM + d] = __float2bfloat16(v * QSCALE);
                } else if (c == 1) {
                    Kb[(size_t)(bh * SEQ + s) * HDIM + d] = __float2bfloat16(v);
                } else {
                    Vt[(size_t)(bh * HDIM + d) * SEQ + s] = __float2bfloat16(v);
                }
            }
        }
    }
}

// ---------------------------------------------------------------------------
// Kernel 2: causal flash attention, single-wave blocks, swapped-operand
// scores (S^T = K·Q^T): q-row lives in lane&15, keys in accumulator regs.
//   -> row stats are in-lane reductions + shfl_xor(16|32) only.
//   -> P writes are packed ds_write_b64 (4 consecutive keys per reg group).
// Software-pipelined: V loads issued before QK, next-chunk K prefetched
// after QK consumes the current frags.
// No __syncthreads: LDS is wave-private, DS pipe is in-order per wave.
// ---------------------------------------------------------------------------
#define P_PITCH 72
__global__ __launch_bounds__(64, 2) void attn_kernel(
    const __hip_bfloat16* __restrict__ Qs,  // [B,H,S,Hd], pre-scaled
    const __hip_bfloat16* __restrict__ Kb,  // [B,H,S,Hd]
    const __hip_bfloat16* __restrict__ Vt,  // [B,H,Hd,S]
    __hip_bfloat16* __restrict__ O)         // [B*S, D]  (cols = h*64+d)
{
    __shared__ __align__(16) __hip_bfloat16 P[32 * P_PITCH];

    const int lane = threadIdx.x;
    const int qb   = gridDim.x - 1 - blockIdx.x;   // heavy blocks first
    const int bh   = blockIdx.y;
    const int base = qb * 32;
    const int lm   = lane & 15;
    const int q4   = lane >> 4;
    const int lk   = q4 * 8;
    const int swz  = (lm & 3) << 4;     // row-keyed XOR swizzle (bits 4..5)

    const __hip_bfloat16* Qbh = Qs + (size_t)bh * SEQ * HDIM;
    const __hip_bfloat16* Kbh = Kb + (size_t)bh * SEQ * HDIM;
    const __hip_bfloat16* Vbh = Vt + (size_t)bh * HDIM * SEQ;

    // Q fragments (B operand): rows = q (lane&15), k = h*32+lk
    short8 qa[2][2];
#pragma unroll
    for (int i = 0; i < 2; ++i)
#pragma unroll
        for (int h = 0; h < 2; ++h)
            qa[i][h] = load8(&Qbh[(size_t)(base + i * 16 + lm) * HDIM + h * 32 + lk]);

    // Per-lane state: q-row = i*16 + lm
    float m_run[2] = {NEG_SENT, NEG_SENT};
    float l_run[2] = {0.f, 0.f};
    f32x4 Oacc[2][4];    // [q-tile][d-tile]; rows = q4*4+r, col = d = t*16+lm
#pragma unroll
    for (int i = 0; i < 2; ++i)
#pragma unroll
        for (int t = 0; t < 4; ++t) Oacc[i][t] = (f32x4){0.f, 0.f, 0.f, 0.f};

    const int nChunks = (base + 32 + 63) >> 6;

    // Preload K frags (A operand) for chunk 0: rows = key t*16+lm
    short8 ka[4][2];
#pragma unroll
    for (int t = 0; t < 4; ++t)
#pragma unroll
        for (int h = 0; h < 2; ++h)
            ka[t][h] = load8(&Kbh[(size_t)(t * 16 + lm) * HDIM + h * 32 + lk]);

    for (int c = 0; c < nChunks; ++c) {
        const int k0 = c * 64;

        // --- issue V loads early (consumed at the end by PV) ---
        short8 vb[4][2];
#pragma unroll
        for (int t = 0; t < 4; ++t)
#pragma unroll
            for (int h = 0; h < 2; ++h)
                vb[t][h] = load8(&Vbh[(size_t)(t * 16 + lm) * SEQ + k0 + h * 32 + lk]);

        // --- scores S^T: D[key t*16+q4*4+r][q-row i*16+lm], 16 MFMAs ---
        f32x4 sc[2][4];
#pragma unroll
        for (int i = 0; i < 2; ++i)
#pragma unroll
            for (int t = 0; t < 4; ++t) sc[i][t] = (f32x4){0.f, 0.f, 0.f, 0.f};
#pragma unroll
        for (int t = 0; t < 4; ++t)
#pragma unroll
            for (int i = 0; i < 2; ++i) {
                sc[i][t] = MFMA_BF16(ka[t][0], qa[i][0], sc[i][t]);
                sc[i][t] = MFMA_BF16(ka[t][1], qa[i][1], sc[i][t]);
            }

        // --- prefetch next chunk's K frags (overlaps softmax + PV) ---
        const int k0n = (c + 1 < nChunks) ? k0 + 64 : k0;
        short8 kn[4][2];
#pragma unroll
        for (int t = 0; t < 4; ++t)
#pragma unroll
            for (int h = 0; h < 2; ++h)
                kn[t][h] = load8(&Kbh[(size_t)(k0n + t * 16 + lm) * HDIM + h * 32 + lk]);

        // --- causal mask (only chunks touching the diagonal) ---
        if (k0 + 63 > base) {
#pragma unroll
            for (int i = 0; i < 2; ++i) {
                const int row = base + i * 16 + lm;
#pragma unroll
                for (int t = 0; t < 4; ++t) {
#pragma unroll
                    for (int r = 0; r < 4; ++r) {
                        const int key = k0 + t * 16 + q4 * 4 + r;
                        if (key > row) sc[i][t][r] = NEG_SENT;
                    }
                }
            }
        }

        // --- online softmax: in-lane over 16 keys + xor16/32 across q4 ---
        float alpha[2];
#pragma unroll
        for (int i = 0; i < 2; ++i) {
            float mx = sc[i][0][0];
#pragma unroll
            for (int t = 0; t < 4; ++t)
#pragma unroll
                for (int r = 0; r < 4; ++r) mx = fmaxf(mx, sc[i][t][r]);
            mx = fmaxf(mx, __shfl_xor(mx, 16));
            mx = fmaxf(mx, __shfl_xor(mx, 32));
            const float mn = fmaxf(m_run[i], mx);
            alpha[i] = exp2f(m_run[i] - mn);
            float s = 0.f;
#pragma unroll
            for (int t = 0; t < 4; ++t)
#pragma unroll
                for (int r = 0; r < 4; ++r) {
                    const float p = exp2f(sc[i][t][r] - mn);
                    sc[i][t][r] = p;
                    s += p;
                }
            s += __shfl_xor(s, 16);
            s += __shfl_xor(s, 32);
            l_run[i] = l_run[i] * alpha[i] + s;
            m_run[i] = mn;
        }

        // --- rescale Oacc: alpha for row q4*4+r lives at lane (q4*4+r) ---
#pragma unroll
        for (int i = 0; i < 2; ++i)
#pragma unroll
            for (int r = 0; r < 4; ++r) {
                const float av = __shfl(alpha[i], q4 * 4 + r);
#pragma unroll
                for (int t = 0; t < 4; ++t) Oacc[i][t][r] *= av;
            }

        // --- P (S^T regs) -> LDS q-major [32][64+pad], packed b64 writes ---
#pragma unroll
        for (int i = 0; i < 2; ++i)
#pragma unroll
            for (int t = 0; t < 4; ++t) {
                short4v pk;
#pragma unroll
                for (int r = 0; r < 4; ++r)
                    pk[r] = (short)__bfloat16_as_ushort(__float2bfloat16(sc[i][t][r]));
                const int col = (t * 16 + q4 * 4) ^ swz;
                *(short4v*)&P[(i * 16 + lm) * P_PITCH + col] = pk;
            }

        // --- PV: A = P rows (q), B = Vt rows (d), 16 MFMAs ---
#pragma unroll
        for (int h = 0; h < 2; ++h) {
            short8 pa[2];
#pragma unroll
            for (int i = 0; i < 2; ++i) {
                const int col = (h * 32 + lk) ^ swz;
                pa[i] = *(const short8*)&P[(i * 16 + lm) * P_PITCH + col];
            }
#pragma unroll
            for (int t = 0; t < 4; ++t)
#pragma unroll
                for (int i = 0; i < 2; ++i)
                    Oacc[i][t] = MFMA_BF16(pa[i], vb[t][h], Oacc[i][t]);
        }

        // --- rotate K prefetch ---
#pragma unroll
        for (int t = 0; t < 4; ++t)
#pragma unroll
            for (int h = 0; h < 2; ++h) ka[t][h] = kn[t][h];
    }

    // --- epilogue: O /= l, store [b*S+s, h*64+d] as bf16 ---
    const int b = bh >> 4;
    const int hh = bh & 15;
#pragma unroll
    for (int i = 0; i < 2; ++i)
#pragma unroll
        for (int r = 0; r < 4; ++r) {
            const float lv = __shfl(l_run[i], q4 * 4 + r);
            const float inv = 1.0f / lv;
            const size_t m = (size_t)b * SEQ + base + i * 16 + q4 * 4 + r;
#pragma unroll
            for (int t = 0; t < 4; ++t)
                O[m * DMODEL + hh * 64 + t * 16 + lm] = __float2bfloat16(Oacc[i][t][r] * inv);
        }
}

// ---------------------------------------------------------------------------
// Kernel 3: out projection.  out[m,n] = sum_k A[m,k] * W[n,k] + bias[n]
// M=4096, K=1024, N=1024.  Output dtype selected by flag (fp32 or bf16).
// ---------------------------------------------------------------------------
__global__ __launch_bounds__(256) void proj_gemm_kernel(
    const __hip_bfloat16* __restrict__ A,     // [4096,1024]
    const __hip_bfloat16* __restrict__ W,     // [1024,1024]
    const __hip_bfloat16* __restrict__ bias,  // [1024]
    void* __restrict__ outv,                  // [4096,1024] fp32 or bf16
    const int* __restrict__ flag)
{
    constexpr int Kd = DMODEL;
    const int lane  = threadIdx.x & 63;
    const int w     = threadIdx.x >> 6;
    const int mBase = blockIdx.y * 128 + (w >> 1) * 64;
    const int nBase = blockIdx.x * 128 + (w & 1) * 64;
    const int lm    = lane & 15;
    const int lk    = (lane >> 4) * 8;
    const bool f32out = (*flag != 0);   // uniform

    f32x4 acc[4][4];
#pragma unroll
    for (int i = 0; i < 4; ++i)
#pragma unroll
        for (int j = 0; j < 4; ++j)
            acc[i][j] = (f32x4){0.f, 0.f, 0.f, 0.f};

    for (int k0 = 0; k0 < Kd; k0 += 32) {
        short8 a[4], b[4];
#pragma unroll
        for (int i = 0; i < 4; ++i)
            a[i] = load8(&A[(size_t)(mBase + i * 16 + lm) * Kd + k0 + lk]);
#pragma unroll
        for (int j = 0; j < 4; ++j)
            b[j] = load8(&W[(size_t)(nBase + j * 16 + lm) * Kd + k0 + lk]);
#pragma unroll
        for (int i = 0; i < 4; ++i)
#pragma unroll
            for (int j = 0; j < 4; ++j)
                acc[i][j] = MFMA_BF16(a[i], b[j], acc[i][j]);
    }

    const int r0 = (lane >> 4) * 4;
#pragma unroll
    for (int j = 0; j < 4; ++j) {
        const int n = nBase + j * 16 + lm;
        const float bv = __bfloat162float(bias[n]);
#pragma unroll
        for (int i = 0; i < 4; ++i) {
#pragma unroll
            for (int r = 0; r < 4; ++r) {
                const size_t m = mBase + i * 16 + r0 + r;
                const float v = acc[i][j][r] + bv;
                if (f32out) ((float*)outv)[m * DMODEL + n] = v;
                else ((__hip_bfloat16*)outv)[m * DMODEL + n] = __float2bfloat16(v);
            }
        }
    }
}

// ---------------------------------------------------------------------------
extern "C" void kernel_launch(void* const* d_in, const int* in_sizes, int n_in,
                              void* d_out, int out_size, void* d_ws, size_t ws_size,
                              hipStream_t stream) {
    // Workspace layout (all 16B-aligned):
    //   [flag:256B][canonical bf16 inputs: X|Wq|bq|Wo|bo][Qs][Kb][Vt][Ao]
    char* wsb = (char*)d_ws;
    int* flag = (int*)wsb;
    __hip_bfloat16* canon = (__hip_bfloat16*)(wsb + 256);
    __hip_bfloat16* Xc = canon;
    __hip_bfloat16* Wq = Xc + N_X;
    __hip_bfloat16* Bq = Wq + N_WQ;
    __hip_bfloat16* Wo = Bq + N_BQ;
    __hip_bfloat16* Bo = Wo + N_WO;

    const size_t nBH = (size_t)BATCH * NHEAD * SEQ * HDIM;  // 4 Mi elements
    __hip_bfloat16* Qs = Bo + N_BO;
    __hip_bfloat16* Kb = Qs + nBH;
    __hip_bfloat16* Vt = Kb + nBH;
    __hip_bfloat16* Ao = Vt + nBH;   // attention output, [B*S, D]

    // 0) detect input dtype (fp32 vs bf16)
    detect_kernel<<<1, 64, 0, stream>>>((const unsigned short*)d_in[1], flag);
    // 0b) canonicalize all inputs to bf16
    canon_kernel<<<(N_CANON + 255) / 256, 256, 0, stream>>>(
        d_in[0], d_in[1], d_in[2], d_in[3], d_in[4], canon, flag);

    // 1) QKV GEMM: M=4096, N=3072
    {
        dim3 grid(3 * DMODEL / 128, NTOK / 128);
        qkv_gemm_kernel<<<grid, 256, 0, stream>>>(Xc, Wq, Bq, Qs, Kb, Vt);
    }
    // 2) Attention: grid (S/32, B*H), single-wave blocks
    {
        dim3 grid(SEQ / 32, BATCH * NHEAD);
        attn_kernel<<<grid, 64, 0, stream>>>(Qs, Kb, Vt, Ao);
    }
    // 3) Out projection: M=4096, N=1024, dtype per flag
    {
        dim3 grid(DMODEL / 128, NTOK / 128);
        proj_gemm_kernel<<<grid, 256, 0, stream>>>(Ao, Wo, Bo, d_out, flag);
    }
}

// Round 5
// 279.162 us; speedup vs baseline: 1.7747x; 1.3685x over previous
//
#include <hip/hip_runtime.h>
#include <hip/hip_bf16.h>

// Sizes (fixed for this problem)
// B=2, S=2048, D=1024, H=16, Hd=64
#define SEQ    2048
#define DMODEL 1024
#define NHEAD  16
#define HDIM   64
#define BATCH  2
#define NTOK   (BATCH * SEQ)           // 4096

// Canonical (bf16) input element counts
#define N_X   (NTOK * DMODEL)          // 4,194,304
#define N_WQ  (3 * DMODEL * DMODEL)    // 3,145,728
#define N_BQ  (3 * DMODEL)             // 3,072
#define N_WO  (DMODEL * DMODEL)        // 1,048,576
#define N_BO  (DMODEL)                 // 1,024
#define N_CANON (N_X + N_WQ + N_BQ + N_WO + N_BO)   // 8,392,704

#define NEG_SENT (-1.0e30f)
// softmax scale folded into Q, in exp2 domain: (1/8) * log2(e)
#define QSCALE 0.1803368801111f

typedef __attribute__((ext_vector_type(8))) short short8;   // 8 x bf16
typedef __attribute__((ext_vector_type(4))) short short4v;  // 4 x bf16 (8 B)
typedef __attribute__((ext_vector_type(4))) float f32x4;

#define MFMA_BF16(A, B, C) __builtin_amdgcn_mfma_f32_16x16x32_bf16((A), (B), (C), 0, 0, 0)

static __device__ __forceinline__ short8 load8(const __hip_bfloat16* p) {
    return *(const short8*)p;
}

// async global->LDS, 16 bytes per lane (gfx950 width-16 variant)
static __device__ __forceinline__ void async16(const void* g, void* l) {
    __builtin_amdgcn_global_load_lds(
        (const __attribute__((address_space(1))) unsigned int*)g,
        (__attribute__((address_space(3))) unsigned int*)l,
        16, 0, 0);
}

// ---------------------------------------------------------------------------
// Kernel 0: dtype detector (round 2 confirmed inputs are fp32; keep the
// runtime check so the kernel is robust either way).
// ---------------------------------------------------------------------------
__global__ void detect_kernel(const unsigned short* __restrict__ w, int* flag) {
    int cnt = 0;
    for (int i = threadIdx.x; i < 512; i += 64) {
        const unsigned e = (w[i] >> 7) & 0xFF;
        if (e >= 125) cnt++;
    }
#pragma unroll
    for (int o = 32; o; o >>= 1) cnt += __shfl_down(cnt, o);
    if (threadIdx.x == 0) *flag = (cnt > 8) ? 1 : 0;
}

// ---------------------------------------------------------------------------
// Kernel 0b: canonicalize all five inputs to bf16 in ws.
// dst layout: [X | Wqkv | bqkv | Wout | bout]
// ---------------------------------------------------------------------------
__global__ __launch_bounds__(256) void canon_kernel(
    const void* __restrict__ s0, const void* __restrict__ s1,
    const void* __restrict__ s2, const void* __restrict__ s3,
    const void* __restrict__ s4,
    __hip_bfloat16* __restrict__ dst, const int* __restrict__ flag)
{
    const int idx = blockIdx.x * 256 + threadIdx.x;
    if (idx >= N_CANON) return;
    const void* src;
    int off;
    if (idx < N_X)                         { src = s0; off = idx; }
    else if (idx < N_X + N_WQ)             { src = s1; off = idx - N_X; }
    else if (idx < N_X + N_WQ + N_BQ)      { src = s2; off = idx - (N_X + N_WQ); }
    else if (idx < N_X + N_WQ + N_BQ + N_WO){ src = s3; off = idx - (N_X + N_WQ + N_BQ); }
    else                                   { src = s4; off = idx - (N_X + N_WQ + N_BQ + N_WO); }
    const bool isf32 = (*flag != 0);   // uniform branch
    const float v = isf32 ? ((const float*)src)[off]
                          : __bfloat162float(((const __hip_bfloat16*)src)[off]);
    dst[idx] = __float2bfloat16(v);
}

// ---------------------------------------------------------------------------
// Kernel 1: QKV GEMM, m97 structure.  C[m,n] = sum_k X[m,k]*W[n,k] + bias[n]
// M=4096, K=1024, N=3072.  128x128 block tile, 4 waves (64x64 each),
// K-step 32 staged via global_load_lds width=16, 2-barrier K-loop.
// Scatter epilogue:
//   c==0: Qs[b,h,s,d] = val * QSCALE
//   c==1: Kb[b,h,s,d] = val
//   c==2: Vt[b,h,d,s] = val   (V transposed for contiguous PV frags)
// ---------------------------------------------------------------------------
__global__ __launch_bounds__(256) void qkv_gemm_kernel(
    const __hip_bfloat16* __restrict__ X,     // [4096,1024]
    const __hip_bfloat16* __restrict__ W,     // [3072,1024]
    const __hip_bfloat16* __restrict__ bias,  // [3072]
    __hip_bfloat16* __restrict__ Qs,
    __hip_bfloat16* __restrict__ Kb,
    __hip_bfloat16* __restrict__ Vt)
{
    constexpr int Kd = DMODEL;
    __shared__ __align__(16) __hip_bfloat16 As[128 * 32];
    __shared__ __align__(16) __hip_bfloat16 Bs[128 * 32];

    const int tid   = threadIdx.x;
    const int lane  = tid & 63;
    const int w     = tid >> 6;
    const int mTile = blockIdx.y * 128;
    const int nTile = blockIdx.x * 128;
    const int wm    = (w >> 1) * 64;        // wave quadrant within tile
    const int wn    = (w & 1) * 64;
    const int lm    = lane & 15;
    const int lk    = (lane >> 4) * 8;

    f32x4 acc[4][4];
#pragma unroll
    for (int i = 0; i < 4; ++i)
#pragma unroll
        for (int j = 0; j < 4; ++j)
            acc[i][j] = (f32x4){0.f, 0.f, 0.f, 0.f};

    // staging chunks: c = tid + 256*p, row = c>>2, 16B pos = c&3
    const int r0c = tid >> 2, p0c = tid & 3;
    const int r1c = (tid + 256) >> 2, p1c = tid & 3;

    for (int k0 = 0; k0 < Kd; k0 += 32) {
        __syncthreads();   // previous iteration's reads complete
        async16(&X[(size_t)(mTile + r0c) * Kd + k0 + p0c * 8], (char*)As + tid * 16);
        async16(&X[(size_t)(mTile + r1c) * Kd + k0 + p1c * 8], (char*)As + tid * 16 + 4096);
        async16(&W[(size_t)(nTile + r0c) * Kd + k0 + p0c * 8], (char*)Bs + tid * 16);
        async16(&W[(size_t)(nTile + r1c) * Kd + k0 + p1c * 8], (char*)Bs + tid * 16 + 4096);
        __syncthreads();   // drain global_load_lds (vmcnt) + barrier

        short8 a[4], b[4];
#pragma unroll
        for (int i = 0; i < 4; ++i)
            a[i] = *(const short8*)&As[(wm + i * 16 + lm) * 32 + lk];
#pragma unroll
        for (int j = 0; j < 4; ++j)
            b[j] = *(const short8*)&Bs[(wn + j * 16 + lm) * 32 + lk];
#pragma unroll
        for (int i = 0; i < 4; ++i)
#pragma unroll
            for (int j = 0; j < 4; ++j)
                acc[i][j] = MFMA_BF16(a[i], b[j], acc[i][j]);
    }

    // Epilogue: C/D layout col = lane&15, row = (lane>>4)*4 + r
    const int r0 = (lane >> 4) * 4;
#pragma unroll
    for (int j = 0; j < 4; ++j) {
        const int n  = nTile + wn + j * 16 + lm;
        const float bv = __bfloat162float(bias[n]);
        const int c = n >> 10;
        const int h = (n >> 6) & 15;
        const int d = n & 63;
#pragma unroll
        for (int i = 0; i < 4; ++i) {
#pragma unroll
            for (int r = 0; r < 4; ++r) {
                const int m  = mTile + wm + i * 16 + r0 + r;
                const int bb = m >> 11;          // / SEQ
                const int s  = m & (SEQ - 1);
                const int bh = bb * NHEAD + h;
                const float v = acc[i][j][r] + bv;
                if (c == 0) {
                    Qs[(size_t)(bh * SEQ + s) * HDIM + d] = __float2bfloat16(v * QSCALE);
                } else if (c == 1) {
                    Kb[(size_t)(bh * SEQ + s) * HDIM + d] = __float2bfloat16(v);
                } else {
                    Vt[(size_t)(bh * HDIM + d) * SEQ + s] = __float2bfloat16(v);
                }
            }
        }
    }
}

// ---------------------------------------------------------------------------
// Kernel 2: causal flash attention, single-wave blocks, swapped-operand
// scores (S^T = K·Q^T).  Unchanged from round 4 (isolating GEMM delta).
// ---------------------------------------------------------------------------
#define P_PITCH 72
__global__ __launch_bounds__(64, 2) void attn_kernel(
    const __hip_bfloat16* __restrict__ Qs,  // [B,H,S,Hd], pre-scaled
    const __hip_bfloat16* __restrict__ Kb,  // [B,H,S,Hd]
    const __hip_bfloat16* __restrict__ Vt,  // [B,H,Hd,S]
    __hip_bfloat16* __restrict__ O)         // [B*S, D]  (cols = h*64+d)
{
    __shared__ __align__(16) __hip_bfloat16 P[32 * P_PITCH];

    const int lane = threadIdx.x;
    const int qb   = gridDim.x - 1 - blockIdx.x;   // heavy blocks first
    const int bh   = blockIdx.y;
    const int base = qb * 32;
    const int lm   = lane & 15;
    const int q4   = lane >> 4;
    const int lk   = q4 * 8;
    const int swz  = (lm & 3) << 4;     // row-keyed XOR swizzle (bits 4..5)

    const __hip_bfloat16* Qbh = Qs + (size_t)bh * SEQ * HDIM;
    const __hip_bfloat16* Kbh = Kb + (size_t)bh * SEQ * HDIM;
    const __hip_bfloat16* Vbh = Vt + (size_t)bh * HDIM * SEQ;

    short8 qa[2][2];
#pragma unroll
    for (int i = 0; i < 2; ++i)
#pragma unroll
        for (int h = 0; h < 2; ++h)
            qa[i][h] = load8(&Qbh[(size_t)(base + i * 16 + lm) * HDIM + h * 32 + lk]);

    float m_run[2] = {NEG_SENT, NEG_SENT};
    float l_run[2] = {0.f, 0.f};
    f32x4 Oacc[2][4];
#pragma unroll
    for (int i = 0; i < 2; ++i)
#pragma unroll
        for (int t = 0; t < 4; ++t) Oacc[i][t] = (f32x4){0.f, 0.f, 0.f, 0.f};

    const int nChunks = (base + 32 + 63) >> 6;

    short8 ka[4][2];
#pragma unroll
    for (int t = 0; t < 4; ++t)
#pragma unroll
        for (int h = 0; h < 2; ++h)
            ka[t][h] = load8(&Kbh[(size_t)(t * 16 + lm) * HDIM + h * 32 + lk]);

    for (int c = 0; c < nChunks; ++c) {
        const int k0 = c * 64;

        short8 vb[4][2];
#pragma unroll
        for (int t = 0; t < 4; ++t)
#pragma unroll
            for (int h = 0; h < 2; ++h)
                vb[t][h] = load8(&Vbh[(size_t)(t * 16 + lm) * SEQ + k0 + h * 32 + lk]);

        f32x4 sc[2][4];
#pragma unroll
        for (int i = 0; i < 2; ++i)
#pragma unroll
            for (int t = 0; t < 4; ++t) sc[i][t] = (f32x4){0.f, 0.f, 0.f, 0.f};
#pragma unroll
        for (int t = 0; t < 4; ++t)
#pragma unroll
            for (int i = 0; i < 2; ++i) {
                sc[i][t] = MFMA_BF16(ka[t][0], qa[i][0], sc[i][t]);
                sc[i][t] = MFMA_BF16(ka[t][1], qa[i][1], sc[i][t]);
            }

        const int k0n = (c + 1 < nChunks) ? k0 + 64 : k0;
        short8 kn[4][2];
#pragma unroll
        for (int t = 0; t < 4; ++t)
#pragma unroll
            for (int h = 0; h < 2; ++h)
                kn[t][h] = load8(&Kbh[(size_t)(k0n + t * 16 + lm) * HDIM + h * 32 + lk]);

        if (k0 + 63 > base) {
#pragma unroll
            for (int i = 0; i < 2; ++i) {
                const int row = base + i * 16 + lm;
#pragma unroll
                for (int t = 0; t < 4; ++t) {
#pragma unroll
                    for (int r = 0; r < 4; ++r) {
                        const int key = k0 + t * 16 + q4 * 4 + r;
                        if (key > row) sc[i][t][r] = NEG_SENT;
                    }
                }
            }
        }

        float alpha[2];
#pragma unroll
        for (int i = 0; i < 2; ++i) {
            float mx = sc[i][0][0];
#pragma unroll
            for (int t = 0; t < 4; ++t)
#pragma unroll
                for (int r = 0; r < 4; ++r) mx = fmaxf(mx, sc[i][t][r]);
            mx = fmaxf(mx, __shfl_xor(mx, 16));
            mx = fmaxf(mx, __shfl_xor(mx, 32));
            const float mn = fmaxf(m_run[i], mx);
            alpha[i] = exp2f(m_run[i] - mn);
            float s = 0.f;
#pragma unroll
            for (int t = 0; t < 4; ++t)
#pragma unroll
                for (int r = 0; r < 4; ++r) {
                    const float p = exp2f(sc[i][t][r] - mn);
                    sc[i][t][r] = p;
                    s += p;
                }
            s += __shfl_xor(s, 16);
            s += __shfl_xor(s, 32);
            l_run[i] = l_run[i] * alpha[i] + s;
            m_run[i] = mn;
        }

#pragma unroll
        for (int i = 0; i < 2; ++i)
#pragma unroll
            for (int r = 0; r < 4; ++r) {
                const float av = __shfl(alpha[i], q4 * 4 + r);
#pragma unroll
                for (int t = 0; t < 4; ++t) Oacc[i][t][r] *= av;
            }

#pragma unroll
        for (int i = 0; i < 2; ++i)
#pragma unroll
            for (int t = 0; t < 4; ++t) {
                short4v pk;
#pragma unroll
                for (int r = 0; r < 4; ++r)
                    pk[r] = (short)__bfloat16_as_ushort(__float2bfloat16(sc[i][t][r]));
                const int col = (t * 16 + q4 * 4) ^ swz;
                *(short4v*)&P[(i * 16 + lm) * P_PITCH + col] = pk;
            }

#pragma unroll
        for (int h = 0; h < 2; ++h) {
            short8 pa[2];
#pragma unroll
            for (int i = 0; i < 2; ++i) {
                const int col = (h * 32 + lk) ^ swz;
                pa[i] = *(const short8*)&P[(i * 16 + lm) * P_PITCH + col];
            }
#pragma unroll
            for (int t = 0; t < 4; ++t)
#pragma unroll
                for (int i = 0; i < 2; ++i)
                    Oacc[i][t] = MFMA_BF16(pa[i], vb[t][h], Oacc[i][t]);
        }

#pragma unroll
        for (int t = 0; t < 4; ++t)
#pragma unroll
            for (int h = 0; h < 2; ++h) ka[t][h] = kn[t][h];
    }

    const int b = bh >> 4;
    const int hh = bh & 15;
#pragma unroll
    for (int i = 0; i < 2; ++i)
#pragma unroll
        for (int r = 0; r < 4; ++r) {
            const float lv = __shfl(l_run[i], q4 * 4 + r);
            const float inv = 1.0f / lv;
            const size_t m = (size_t)b * SEQ + base + i * 16 + q4 * 4 + r;
#pragma unroll
            for (int t = 0; t < 4; ++t)
                O[m * DMODEL + hh * 64 + t * 16 + lm] = __float2bfloat16(Oacc[i][t][r] * inv);
        }
}

// ---------------------------------------------------------------------------
// Kernel 3: out projection, m97 structure.  M=4096, K=1024, N=1024.
// Output dtype selected by flag (fp32 or bf16).
// ---------------------------------------------------------------------------
__global__ __launch_bounds__(256) void proj_gemm_kernel(
    const __hip_bfloat16* __restrict__ A,     // [4096,1024]
    const __hip_bfloat16* __restrict__ W,     // [1024,1024]
    const __hip_bfloat16* __restrict__ bias,  // [1024]
    void* __restrict__ outv,                  // [4096,1024] fp32 or bf16
    const int* __restrict__ flag)
{
    constexpr int Kd = DMODEL;
    __shared__ __align__(16) __hip_bfloat16 As[128 * 32];
    __shared__ __align__(16) __hip_bfloat16 Bs[128 * 32];

    const int tid   = threadIdx.x;
    const int lane  = tid & 63;
    const int w     = tid >> 6;
    const int mTile = blockIdx.y * 128;
    const int nTile = blockIdx.x * 128;
    const int wm    = (w >> 1) * 64;
    const int wn    = (w & 1) * 64;
    const int lm    = lane & 15;
    const int lk    = (lane >> 4) * 8;
    const bool f32out = (*flag != 0);   // uniform

    f32x4 acc[4][4];
#pragma unroll
    for (int i = 0; i < 4; ++i)
#pragma unroll
        for (int j = 0; j < 4; ++j)
            acc[i][j] = (f32x4){0.f, 0.f, 0.f, 0.f};

    const int r0c = tid >> 2, p0c = tid & 3;
    const int r1c = (tid + 256) >> 2, p1c = tid & 3;

    for (int k0 = 0; k0 < Kd; k0 += 32) {
        __syncthreads();
        async16(&A[(size_t)(mTile + r0c) * Kd + k0 + p0c * 8], (char*)As + tid * 16);
        async16(&A[(size_t)(mTile + r1c) * Kd + k0 + p1c * 8], (char*)As + tid * 16 + 4096);
        async16(&W[(size_t)(nTile + r0c) * Kd + k0 + p0c * 8], (char*)Bs + tid * 16);
        async16(&W[(size_t)(nTile + r1c) * Kd + k0 + p1c * 8], (char*)Bs + tid * 16 + 4096);
        __syncthreads();

        short8 a[4], b[4];
#pragma unroll
        for (int i = 0; i < 4; ++i)
            a[i] = *(const short8*)&As[(wm + i * 16 + lm) * 32 + lk];
#pragma unroll
        for (int j = 0; j < 4; ++j)
            b[j] = *(const short8*)&Bs[(wn + j * 16 + lm) * 32 + lk];
#pragma unroll
        for (int i = 0; i < 4; ++i)
#pragma unroll
            for (int j = 0; j < 4; ++j)
                acc[i][j] = MFMA_BF16(a[i], b[j], acc[i][j]);
    }

    const int r0 = (lane >> 4) * 4;
#pragma unroll
    for (int j = 0; j < 4; ++j) {
        const int n = nTile + wn + j * 16 + lm;
        const float bv = __bfloat162float(bias[n]);
#pragma unroll
        for (int i = 0; i < 4; ++i) {
#pragma unroll
            for (int r = 0; r < 4; ++r) {
                const size_t m = mTile + wm + i * 16 + r0 + r;
                const float v = acc[i][j][r] + bv;
                if (f32out) ((float*)outv)[m * DMODEL + n] = v;
                else ((__hip_bfloat16*)outv)[m * DMODEL + n] = __float2bfloat16(v);
            }
        }
    }
}

// ---------------------------------------------------------------------------
extern "C" void kernel_launch(void* const* d_in, const int* in_sizes, int n_in,
                              void* d_out, int out_size, void* d_ws, size_t ws_size,
                              hipStream_t stream) {
    // Workspace layout (all 16B-aligned):
    //   [flag:256B][canonical bf16 inputs: X|Wq|bq|Wo|bo][Qs][Kb][Vt][Ao]
    char* wsb = (char*)d_ws;
    int* flag = (int*)wsb;
    __hip_bfloat16* canon = (__hip_bfloat16*)(wsb + 256);
    __hip_bfloat16* Xc = canon;
    __hip_bfloat16* Wq = Xc + N_X;
    __hip_bfloat16* Bq = Wq + N_WQ;
    __hip_bfloat16* Wo = Bq + N_BQ;
    __hip_bfloat16* Bo = Wo + N_WO;

    const size_t nBH = (size_t)BATCH * NHEAD * SEQ * HDIM;  // 4 Mi elements
    __hip_bfloat16* Qs = Bo + N_BO;
    __hip_bfloat16* Kb = Qs + nBH;
    __hip_bfloat16* Vt = Kb + nBH;
    __hip_bfloat16* Ao = Vt + nBH;   // attention output, [B*S, D]

    // 0) detect input dtype (fp32 vs bf16)
    detect_kernel<<<1, 64, 0, stream>>>((const unsigned short*)d_in[1], flag);
    // 0b) canonicalize all inputs to bf16
    canon_kernel<<<(N_CANON + 255) / 256, 256, 0, stream>>>(
        d_in[0], d_in[1], d_in[2], d_in[3], d_in[4], canon, flag);

    // 1) QKV GEMM: M=4096, N=3072
    {
        dim3 grid(3 * DMODEL / 128, NTOK / 128);
        qkv_gemm_kernel<<<grid, 256, 0, stream>>>(Xc, Wq, Bq, Qs, Kb, Vt);
    }
    // 2) Attention: grid (S/32, B*H), single-wave blocks
    {
        dim3 grid(SEQ / 32, BATCH * NHEAD);
        attn_kernel<<<grid, 64, 0, stream>>>(Qs, Kb, Vt, Ao);
    }
    // 3) Out projection: M=4096, N=1024, dtype per flag
    {
        dim3 grid(DMODEL / 128, NTOK / 128);
        proj_gemm_kernel<<<grid, 256, 0, stream>>>(Ao, Wo, Bo, d_out, flag);
    }
}